// Round 5
// baseline (459.604 us; speedup 1.0000x reference)
//
#include <hip/hip_runtime.h>
#include <hip/hip_bf16.h>
#include <stdint.h>

#define B_ROWS 16384
#define D_K    2048
#define C_COLS 1000
#define C_PAD  1024
#define EPS_D2 1e-12f

typedef __attribute__((ext_vector_type(8))) short bf16x8;
typedef __attribute__((ext_vector_type(4))) float f32x4;

__device__ __forceinline__ void async16(void* lds, const void* g) {
    __builtin_amdgcn_global_load_lds(
        (const __attribute__((address_space(1))) unsigned int*)g,
        (__attribute__((address_space(3))) unsigned int*)lds,
        16, 0, 0);
}

// 4 f32 -> 4 bf16 (RNE) packed into uint2
__device__ __forceinline__ uint2 pack_bf16x4(float4 v) {
    union { __hip_bfloat162 h; uint32_t u; } a, b;
    a.h = __float22bfloat162_rn(make_float2(v.x, v.y));
    b.h = __float22bfloat162_rn(make_float2(v.z, v.w));
    uint2 r; r.x = a.u; r.y = b.u; return r;
}

// w-only prep: fp32 -> bf16 (rows >= C_COLS zero-padded) + ||w||^2. ~8 MB traffic.
__global__ __launch_bounds__(256) void wprep(
    const float* __restrict__ w, __hip_bfloat16* __restrict__ wb, float* __restrict__ w2) {
    const int t = threadIdx.x;
    const int wave = t >> 6;
    const int lane = t & 63;
    const int row = blockIdx.x * 4 + wave;          // 0..1023
    const bool valid = (row < C_COLS);

    const float* src = w + (size_t)row * D_K;
    uint4* dst = (uint4*)(wb + (size_t)row * D_K);

    float4 v[8];
    if (valid) {
        const float4* s4 = (const float4*)src;
        #pragma unroll
        for (int i = 0; i < 4; i++) {
            v[2 * i]     = s4[2 * lane + 128 * i];
            v[2 * i + 1] = s4[2 * lane + 1 + 128 * i];
        }
    } else {
        #pragma unroll
        for (int i = 0; i < 8; i++) v[i] = make_float4(0.f, 0.f, 0.f, 0.f);
    }
    float ss = 0.f;
    #pragma unroll
    for (int i = 0; i < 8; i++)
        ss += v[i].x * v[i].x + v[i].y * v[i].y + v[i].z * v[i].z + v[i].w * v[i].w;
    #pragma unroll
    for (int i = 0; i < 4; i++) {
        uint2 a = pack_bf16x4(v[2 * i]);
        uint2 b = pack_bf16x4(v[2 * i + 1]);
        uint4 p; p.x = a.x; p.y = a.y; p.z = b.x; p.w = b.y;
        dst[lane + 64 * i] = p;
    }
    #pragma unroll
    for (int off = 32; off > 0; off >>= 1) ss += __shfl_down(ss, off, 64);
    if (lane == 0) w2[row] = valid ? ss : 0.f;
}

// Fused GEMM: A read fp32 direct-from-global into registers (no LDS, no prep pass),
// in-register bf16 convert + fused ||x||^2; B double-buffered in LDS with
// prefetch-at-top-of-iter (full MFMA section covers each drain); 1 barrier/iter.
// 128x128 tile, BK=32, 4 waves (2x2), 4x4 MFMA 16x16x32 per wave.
__global__ __launch_bounds__(256) void dml_fused(
    const float* __restrict__ X,            // [16384, 2048] fp32
    const __hip_bfloat16* __restrict__ Wb,  // [1024, 2048] bf16 (padded)
    const float* __restrict__ w2,           // [1024]
    const float* __restrict__ scales, float* __restrict__ out)
{
    __shared__ __align__(16) char smem[32 * 132 * 4];   // 16896 B; K-loop: B dbuf 2x8192
    __hip_bfloat16* lsB = (__hip_bfloat16*)smem;
    float* lsC = (float*)smem;                          // epilogue alias
    __shared__ float sx2[128];

    const int tid  = threadIdx.x;
    const int wave = tid >> 6;
    const int lane = tid & 63;

    // XCD-aware remap (gridDim.x == 8): XCD x owns m-tiles [x*16, x*16+16).
    const int id  = blockIdx.y * 8 + blockIdx.x;
    const int xcd = id & 7;
    const int j   = id >> 3;
    const int m0  = (xcd * 16 + (j >> 3)) * 128;
    const int n0  = (j & 7) * 128;

    const int wm = wave >> 1;
    const int wn = wave & 1;

    // B staging (swizzled, 16B/lane): wave covers rows wave*32+(lane>>2)+{0,16}
    const int srow = wave * 32 + (lane >> 2);
    const int slot = lane & 3;
    const int scol = (slot ^ ((srow >> 1) & 3)) * 8;
    const __hip_bfloat16* gB0 = Wb + (size_t)(n0 + srow) * D_K + scol;
    const __hip_bfloat16* gB1 = gB0 + (size_t)16 * D_K;
    const int lBoff = wave * 32 * 64 + lane * 16;       // bytes within one B buffer

    // B fragment read (swizzled)
    const int fr  = lane & 15;
    const int fq  = lane >> 4;
    const int fsw = (fr >> 1) & 3;
    const int fBoff = (wn * 64 + fr) * 32 + (fq ^ fsw) * 8;   // elements within buffer

    // A direct: lane's frag row = m0 + wm*64 + i*16 + fr, cols fq*8 + 32k .. +8
    const float* gA = X + (size_t)(m0 + wm * 64 + fr) * D_K + fq * 8;

    f32x4 acc[4][4] = {};
    float ss[4] = {0.f, 0.f, 0.f, 0.f};

    // Prologue: A(0) into regs, B(0) into buf0.
    float4 vA0[4], vA1[4];
    #pragma unroll
    for (int i = 0; i < 4; i++) {
        const float* p = gA + (size_t)i * 16 * D_K;
        vA0[i] = *(const float4*)p;
        vA1[i] = *(const float4*)(p + 4);
    }
    async16((char*)lsB + lBoff, gB0);
    async16((char*)lsB + lBoff + 16 * 64, gB1);

    for (int k = 0; k < 64; k++) {
        const int buf = k & 1;
        __syncthreads();   // drains B(k) async16 + vA(k) loads — all issued one iter ago,
                           // covered by the previous iteration's ds_read+MFMA section

        // Convert A(k) regs -> bf16 frags; accumulate ||x||^2 (fp32, wave-local)
        bf16x8 a[4];
        #pragma unroll
        for (int i = 0; i < 4; i++) {
            float4 u = vA0[i], v = vA1[i];
            ss[i] += u.x * u.x + u.y * u.y + u.z * u.z + u.w * u.w
                   + v.x * v.x + v.y * v.y + v.z * v.z + v.w * v.w;
            union { bf16x8 v8; uint2 u2[2]; } pk;
            pk.u2[0] = pack_bf16x4(u);
            pk.u2[1] = pack_bf16x4(v);
            a[i] = pk.v8;
        }

        // Prefetch next iter's A regs + B tile (drained at next iter's barrier)
        if (k < 63) {
            const float* gAn = gA + (k + 1) * 32;
            #pragma unroll
            for (int i = 0; i < 4; i++) {
                const float* p = gAn + (size_t)i * 16 * D_K;
                vA0[i] = *(const float4*)p;
                vA1[i] = *(const float4*)(p + 4);
            }
            async16((char*)lsB + (buf ^ 1) * 8192 + lBoff, gB0 + (k + 1) * 32);
            async16((char*)lsB + (buf ^ 1) * 8192 + lBoff + 16 * 64, gB1 + (k + 1) * 32);
        }

        const __hip_bfloat16* fBb = lsB + buf * 4096 + fBoff;
        bf16x8 b[4];
        #pragma unroll
        for (int j2 = 0; j2 < 4; j2++) b[j2] = *(const bf16x8*)(fBb + j2 * 16 * 32);
        #pragma unroll
        for (int i = 0; i < 4; i++)
            #pragma unroll
            for (int j2 = 0; j2 < 4; j2++)
                acc[i][j2] = __builtin_amdgcn_mfma_f32_16x16x32_bf16(a[i], b[j2], acc[i][j2], 0, 0, 0);
    }

    // ||x||^2: reduce over the 4 fq-lane groups (lane = fq*16 + fr)
    #pragma unroll
    for (int i = 0; i < 4; i++) {
        float v = ss[i];
        v += __shfl_xor(v, 16, 64);
        v += __shfl_xor(v, 32, 64);
        ss[i] = v;
    }
    if (wn == 0 && fq == 0) {
        #pragma unroll
        for (int i = 0; i < 4; i++) sx2[wm * 64 + i * 16 + fr] = ss[i];
    }
    __syncthreads();   // sx2 visible; all B ds_reads done -> lsC alias safe

    // Epilogue: -s*sqrt(max(x2+w2-2*acc, eps)), LDS-staged, aligned float4 stores.
    const float s = scales[0];
    const int colb  = wn * 64 + fr;
    const int rowlb = wm * 64 + fq * 4;

    float w2v[4];
    #pragma unroll
    for (int j2 = 0; j2 < 4; j2++) w2v[j2] = w2[n0 + colb + j2 * 16];
    float x2v[4][4];
    #pragma unroll
    for (int i = 0; i < 4; i++)
        #pragma unroll
        for (int r = 0; r < 4; r++) x2v[i][r] = sx2[rowlb + i * 16 + r];

    const int rr  = tid >> 3;
    const int gmb = m0 + (rr & 15) + (rr >> 4) * 64;
    #pragma unroll
    for (int i = 0; i < 4; i++) {
        #pragma unroll
        for (int j2 = 0; j2 < 4; j2++)
            #pragma unroll
            for (int r = 0; r < 4; r++) {
                float d2 = x2v[i][r] + w2v[j2] - 2.0f * acc[i][j2][r];
                d2 = fmaxf(d2, EPS_D2);
                lsC[(wm * 16 + fq * 4 + r) * 132 + colb + j2 * 16] = -s * __builtin_sqrtf(d2);
            }
        __syncthreads();
        {
            float* orow = out + (size_t)(gmb + i * 16) * C_COLS + n0;
            #pragma unroll
            for (int q = 0; q < 4; q++) {
                const int f = (tid & 7) + 8 * q;
                if ((n0 >> 2) + f < C_COLS / 4) {
                    float4 val = *(const float4*)(lsC + rr * 132 + f * 4);
                    *(float4*)(orow + f * 4) = val;
                }
            }
        }
        __syncthreads();
    }
}

extern "C" void kernel_launch(void* const* d_in, const int* in_sizes, int n_in,
                              void* d_out, int out_size, void* d_ws, size_t ws_size,
                              hipStream_t stream) {
    const float* x      = (const float*)d_in[0];
    const float* w      = (const float*)d_in[1];
    const float* scales = (const float*)d_in[2];
    float* out = (float*)d_out;

    char* ws = (char*)d_ws;
    __hip_bfloat16* wb = (__hip_bfloat16*)ws;                        // 4,194,304 B
    float* w2 = (float*)(ws + (size_t)C_PAD * D_K * 2);              // 4,096 B

    wprep<<<dim3(C_PAD / 4), dim3(256), 0, stream>>>(w, wb, w2);
    dml_fused<<<dim3(8, B_ROWS / 128), dim3(256), 0, stream>>>(x, wb, w2, scales, out);
}